// Round 12
// baseline (1314.328 us; speedup 1.0000x reference)
//
#include <hip/hip_runtime.h>
#include <math.h>

// PLRNN forward via MFMA matvec. 256 batches x 1024 steps, 1 WG (512 thr,
// 8 waves) per batch, 1 per CU. Weights resident as f16 MFMA fragments.
// R4 skeleton + 2D-split phase 2 (2M x 4K, the op-model optimum d=4):
//   p1 (M-split): wave w -> pre rows [64w,64w+64): 4x4 MFMA, C-in = h2.
//   bounce (masked): relu+f16 -> rt[64w..64w+64), 4 ops.
//   p2 (2Mx4K): wave w (m2=w&1, k2=w>>1) -> rows [64m2,64m2+64) over
//       k in [128k2,128k2+128): 4mt x 4kt MFMA. Own-half k-tiles (= own
//       bounce rows, offset 64m2) computed PRE-B0; partner half post-B0.
//   pwrite: masked f32x4 -> part[k2][64m2+16mt+4g] (conflict-free). B1.
//   update (wave w, rows 16w..16w+16, masked lanes): u = sum_4 part + tailv
//       (tail MFMA = [C|h1]x[s~|1], issued at step start, off-chain);
//       znew = A*zf + u; TF via Xc; publish zf_h; wave 7 stages s~(t+1). B2.
// X/S/out staged in LDS per 128-step chunk -> no global ops in steady state.

#define NB 256
#define T  1024
#define DX 64
#define DZ 128
#define DH 512
#define DS 16
#define CHUNK 128
#define PP 132              // part row stride (floats)

typedef _Float16 half8 __attribute__((ext_vector_type(8)));
typedef _Float16 v4h   __attribute__((ext_vector_type(4)));
typedef float    f32x4 __attribute__((ext_vector_type(4)));

__device__ __forceinline__ half8 cvt8(const float* __restrict__ src) {
  const float4 a = *reinterpret_cast<const float4*>(src);
  const float4 c = *reinterpret_cast<const float4*>(src + 4);
  half8 h;
  h[0] = (_Float16)a.x; h[1] = (_Float16)a.y; h[2] = (_Float16)a.z; h[3] = (_Float16)a.w;
  h[4] = (_Float16)c.x; h[5] = (_Float16)c.y; h[6] = (_Float16)c.z; h[7] = (_Float16)c.w;
  return h;
}

__global__ __launch_bounds__(512, 2) void plrnn_kernel(
    const float* __restrict__ X, const float* __restrict__ S,
    const float* __restrict__ A, const float* __restrict__ W1,
    const float* __restrict__ W2, const float* __restrict__ h1,
    const float* __restrict__ h2, const float* __restrict__ C,
    float* __restrict__ out)
{
  __shared__ __align__(16) _Float16 zf_h[DZ];          // 256 B
  __shared__ __align__(16) _Float16 rt[544];           // r(512)+s~(16)+[1,0..](16)
  __shared__ __align__(16) float    part[4][PP];       // 2.1 KiB
  __shared__ __align__(16) float    Xc[CHUNK][DX];     // 32 KiB: X[t+1 .. t+128]
  __shared__ __align__(16) float    Sc[CHUNK][DS];     // 8 KiB:  S[t .. t+127]
  __shared__ __align__(16) float    outc[CHUNK][DX];   // 32 KiB

  const int b   = blockIdx.x;
  const int tid = threadIdx.x;
  const int w   = tid >> 6;            // wave 0..7
  const int l   = tid & 63;
  const int g   = l >> 4;              // 16-lane group (B k-slice / D row-block)
  const int r15 = l & 15;              // A row-in-tile / D col
  const int m2  = w & 1;               // p2 M-group (rows 64*m2..+64)
  const int k2  = w >> 1;              // p2 K-group (k 128*k2..+128)

  // ---- one-time: stage chunk 0 (X rows 1..128 clamped, S rows 0..127) ----
  {
    #pragma unroll
    for (int k = 0; k < 4; ++k) {
      const int flat = k * 2048 + tid * 4;
      int srow = 1 + (flat >> 6);
      if (srow > T - 1) srow = T - 1;
      const float4 v = *reinterpret_cast<const float4*>(X + ((size_t)b * T + srow) * DX + (flat & 63));
      *reinterpret_cast<float4*>(&((float*)Xc)[flat]) = v;
    }
    const int flat = tid * 4;
    const float4 v = *reinterpret_cast<const float4*>(S + ((size_t)b * T) * DS + flat);
    *reinterpret_cast<float4*>(&((float*)Sc)[flat]) = v;
  }

  // ---- one-time: rt tail: s~(0) + [1,0..0] constant block ----
  if (tid < 16) {
    rt[512 + tid] = (_Float16)S[((size_t)b * T) * DS + tid];
    rt[528 + tid] = (tid == 0) ? (_Float16)1.0f : (_Float16)0.0f;
  }

  // ---- one-time: W2 A-fragments (wave w: rows 64w+16mt+r15, k=32kt+8g+e) ----
  half8 w2f[4][4];
  #pragma unroll
  for (int mt = 0; mt < 4; ++mt)
    #pragma unroll
    for (int kt = 0; kt < 4; ++kt)
      w2f[mt][kt] = cvt8(W2 + ((size_t)b * DH + 64 * w + 16 * mt + r15) * DZ + 32 * kt + 8 * g);

  // ---- one-time: W1 A-fragments for 2Mx4K p2, own-k-first order ----
  // slot j: j<2 -> own half (kt = 2*m2 + j), j>=2 -> partner (kt = 2*(1-m2)+j-2)
  half8 w1f[4][4];
  #pragma unroll
  for (int mt = 0; mt < 4; ++mt)
    #pragma unroll
    for (int j = 0; j < 4; ++j) {
      const int kt = (j < 2) ? (2 * m2 + j) : (2 * (1 - m2) + (j - 2));
      w1f[mt][j] = cvt8(W1 + ((size_t)b * DZ + 64 * m2 + 16 * mt + r15) * DH
                           + 128 * k2 + 32 * kt + 8 * g);
    }

  // ---- one-time: tail A-fragment (rows 16w+r15): [C | h1 | 0] ----
  half8 w1ft;
  #pragma unroll
  for (int e = 0; e < 8; ++e) w1ft[e] = (_Float16)0.0f;
  {
    const int row = 16 * w + r15;
    if (g == 0)      w1ft = cvt8(C + ((size_t)b * DZ + row) * DS + 0);
    else if (g == 1) w1ft = cvt8(C + ((size_t)b * DZ + row) * DS + 8);
    else if (g == 2) w1ft[0] = (_Float16)h1[(size_t)b * DZ + row];
  }

  // ---- one-time: h2 as acc-init (D rows 4g+j of each mt) ----
  f32x4 h2v[4];
  #pragma unroll
  for (int mt = 0; mt < 4; ++mt)
    h2v[mt] = *reinterpret_cast<const f32x4*>(h2 + (size_t)b * DH + 64 * w + 16 * mt + 4 * g);

  // ---- one-time: update constants (rows 16w+4g+j on r15==0 lanes) ----
  f32x4 Areg = {0.f, 0.f, 0.f, 0.f};
  f32x4 zfcur = {0.f, 0.f, 0.f, 0.f};
  if (r15 == 0) {
    Areg = *reinterpret_cast<const f32x4*>(A + (size_t)b * DZ + 16 * w + 4 * g);
    if (w < 4) {
      const f32x4 x0 = *reinterpret_cast<const f32x4*>(X + ((size_t)b * T) * DX + 16 * w + 4 * g);
      #pragma unroll
      for (int j = 0; j < 4; ++j) zfcur[j] = (x0[j] != x0[j]) ? 0.f : x0[j];  // zf(0)
    }
    v4h zp;
    #pragma unroll
    for (int j = 0; j < 4; ++j) zp[j] = (_Float16)zfcur[j];
    *reinterpret_cast<v4h*>(&zf_h[16 * w + 4 * g]) = zp;
  }
  __syncthreads();

  const f32x4 zero4 = {0.f, 0.f, 0.f, 0.f};

  for (int t = 0; t < T; ++t) {
    // ---- chunk boundary: flush out-chunk, stage next X/S chunk + s~ ----
    if ((t & (CHUNK - 1)) == 0 && t) {
      const int c0 = t - CHUNK;
      #pragma unroll
      for (int k = 0; k < 4; ++k) {
        const int flat = k * 2048 + tid * 4;
        const float4 v = *reinterpret_cast<const float4*>(&((float*)outc)[flat]);
        *reinterpret_cast<float4*>(out + ((size_t)b * T + c0) * DX + flat) = v;
      }
      #pragma unroll
      for (int k = 0; k < 4; ++k) {
        const int flat = k * 2048 + tid * 4;
        int srow = t + 1 + (flat >> 6);
        if (srow > T - 1) srow = T - 1;
        const float4 v = *reinterpret_cast<const float4*>(X + ((size_t)b * T + srow) * DX + (flat & 63));
        *reinterpret_cast<float4*>(&((float*)Xc)[flat]) = v;
      }
      {
        const int flat = tid * 4;
        const float4 v = *reinterpret_cast<const float4*>(S + ((size_t)b * T + t) * DS + flat);
        *reinterpret_cast<float4*>(&((float*)Sc)[flat]) = v;
      }
      if (tid < 16) rt[512 + tid] = (_Float16)S[((size_t)b * T + t) * DS + tid];
      __syncthreads();
    }
    const int tc = t & (CHUNK - 1);

    // ---- off-chain tail MFMA: tailv rows 16w+4g+j = C·s~ + h1 ----
    const half8 brt = *reinterpret_cast<const half8*>(rt + 512 + 8 * g);
    const f32x4 tailv = __builtin_amdgcn_mfma_f32_16x16x32_f16(w1ft, brt, zero4, 0, 0, 0);

    // ---- phase 1: pre = h2 + W2·zf (16 MFMA, 4 chains) ----
    half8 bz[4];
    #pragma unroll
    for (int kt = 0; kt < 4; ++kt)
      bz[kt] = *reinterpret_cast<const half8*>(zf_h + 32 * kt + 8 * g);

    f32x4 acc1[4];
    #pragma unroll
    for (int mt = 0; mt < 4; ++mt)
      acc1[mt] = __builtin_amdgcn_mfma_f32_16x16x32_f16(w2f[mt][0], bz[0], h2v[mt], 0, 0, 0);
    #pragma unroll
    for (int kt = 1; kt < 4; ++kt)
      #pragma unroll
      for (int mt = 0; mt < 4; ++mt)
        acc1[mt] = __builtin_amdgcn_mfma_f32_16x16x32_f16(w2f[mt][kt], bz[kt], acc1[mt], 0, 0, 0);

    // ---- bounce (masked): relu+f16 -> rt[64w..64w+64), 4 ops ----
    if (r15 == 0) {
      #pragma unroll
      for (int mt = 0; mt < 4; ++mt) {
        v4h p;
        p[0] = (_Float16)fmaxf(acc1[mt][0], 0.f);
        p[1] = (_Float16)fmaxf(acc1[mt][1], 0.f);
        p[2] = (_Float16)fmaxf(acc1[mt][2], 0.f);
        p[3] = (_Float16)fmaxf(acc1[mt][3], 0.f);
        *reinterpret_cast<v4h*>(&rt[64 * w + 16 * mt + 4 * g]) = p;
      }
    }

    // ---- phase 2 pre-B0: OWN k-half (rows this wave just bounced) ----
    f32x4 acc2[4];
    {
      const half8 brA0 = *reinterpret_cast<const half8*>(rt + 64 * w + 8 * g);
      const half8 brA1 = *reinterpret_cast<const half8*>(rt + 64 * w + 32 + 8 * g);
      #pragma unroll
      for (int mt = 0; mt < 4; ++mt)
        acc2[mt] = __builtin_amdgcn_mfma_f32_16x16x32_f16(w1f[mt][0], brA0, zero4, 0, 0, 0);
      #pragma unroll
      for (int mt = 0; mt < 4; ++mt)
        acc2[mt] = __builtin_amdgcn_mfma_f32_16x16x32_f16(w1f[mt][1], brA1, acc2[mt], 0, 0, 0);
    }
    __syncthreads();   // B0: all waves' bounce visible

    // ---- phase 2 post-B0: partner k-half ----
    {
      const int pbase = 128 * k2 + 64 * (1 - m2);
      const half8 brB0 = *reinterpret_cast<const half8*>(rt + pbase + 8 * g);
      const half8 brB1 = *reinterpret_cast<const half8*>(rt + pbase + 32 + 8 * g);
      #pragma unroll
      for (int mt = 0; mt < 4; ++mt)
        acc2[mt] = __builtin_amdgcn_mfma_f32_16x16x32_f16(w1f[mt][2], brB0, acc2[mt], 0, 0, 0);
      #pragma unroll
      for (int mt = 0; mt < 4; ++mt)
        acc2[mt] = __builtin_amdgcn_mfma_f32_16x16x32_f16(w1f[mt][3], brB1, acc2[mt], 0, 0, 0);
    }

    // ---- pwrite (masked, conflict-free): part[k2][64m2+16mt+4g] ----
    if (r15 == 0) {
      #pragma unroll
      for (int mt = 0; mt < 4; ++mt)
        *reinterpret_cast<f32x4*>(&part[k2][64 * m2 + 16 * mt + 4 * g]) = acc2[mt];
    }
    __syncthreads();   // B1: partials visible

    // ---- update (wave w, rows 16w+4g..+4 on masked lanes) ----
    if (r15 == 0) {
      const int row = 16 * w + 4 * g;
      const f32x4 u = (*reinterpret_cast<const f32x4*>(&part[0][row])
                     + *reinterpret_cast<const f32x4*>(&part[1][row]))
                    + (*reinterpret_cast<const f32x4*>(&part[2][row])
                     + *reinterpret_cast<const f32x4*>(&part[3][row]))
                    + tailv;
      f32x4 zn, zfn;
      #pragma unroll
      for (int j = 0; j < 4; ++j) zn[j] = Areg[j] * zfcur[j] + u[j];
      zfn = zn;
      if (w < 4) {
        *reinterpret_cast<f32x4*>(&outc[tc][row]) = zn;
        const f32x4 xv = *reinterpret_cast<const f32x4*>(&Xc[tc][row]);
        #pragma unroll
        for (int j = 0; j < 4; ++j)
          zfn[j] = (xv[j] != xv[j]) ? zn[j] : (0.125f * xv[j] + 0.875f * zn[j]);
      }
      zfcur = zfn;
      v4h zp;
      #pragma unroll
      for (int j = 0; j < 4; ++j) zp[j] = (_Float16)zfn[j];
      *reinterpret_cast<v4h*>(&zf_h[row]) = zp;
    }
    // ---- stage s~(t+1) (wave 7; chunk-boundary block restages otherwise) ----
    if (w == 7 && l < 4 && ((t + 1) & (CHUNK - 1)) != 0) {
      const f32x4 sv = *reinterpret_cast<const f32x4*>(&Sc[(t + 1) & (CHUNK - 1)][4 * l]);
      v4h sp;
      #pragma unroll
      for (int j = 0; j < 4; ++j) sp[j] = (_Float16)sv[j];
      *reinterpret_cast<v4h*>(&rt[512 + 4 * l]) = sp;
    }
    __syncthreads();   // B2: zf(t+1) + s~(t+1) visible
  }

  // ---- final flush (last chunk) ----
  {
    const int c0 = T - CHUNK;
    #pragma unroll
    for (int k = 0; k < 4; ++k) {
      const int flat = k * 2048 + tid * 4;
      const float4 v = *reinterpret_cast<const float4*>(&((float*)outc)[flat]);
      *reinterpret_cast<float4*>(out + ((size_t)b * T + c0) * DX + flat) = v;
    }
  }
}

extern "C" void kernel_launch(void* const* d_in, const int* in_sizes, int n_in,
                              void* d_out, int out_size, void* d_ws, size_t ws_size,
                              hipStream_t stream) {
  const float* X  = (const float*)d_in[0];
  const float* S  = (const float*)d_in[1];
  const float* A  = (const float*)d_in[2];
  const float* W1 = (const float*)d_in[3];
  const float* W2 = (const float*)d_in[4];
  const float* h1 = (const float*)d_in[5];
  const float* h2 = (const float*)d_in[6];
  const float* C  = (const float*)d_in[7];
  float* out = (float*)d_out;
  plrnn_kernel<<<dim3(NB), dim3(512), 0, stream>>>(X, S, A, W1, W2, h1, h2, C, out);
}